// Round 21
// baseline (323.621 us; speedup 1.0000x reference)
//
#include <hip/hip_runtime.h>

#define B_N 16384
#define D_K 512
#define C_N 1000
#define CP 1024
#define M_N 8
#define GAP_EPS 1e-3f

typedef __attribute__((ext_vector_type(8))) _Float16 f16x8;
typedef __attribute__((ext_vector_type(4))) float f32x4;

typedef const __attribute__((address_space(1))) unsigned int* gptr_t;
typedef __attribute__((address_space(3))) unsigned int* lptr_t;

__device__ __forceinline__ void gload16(const void* g, void* l) {
    __builtin_amdgcn_global_load_lds((gptr_t)g, (lptr_t)l, 16, 0, 0);
}

#define BAR()        asm volatile("s_barrier" ::: "memory")
#define WAIT_LGKM0() asm volatile("s_waitcnt lgkmcnt(0)" ::: "memory")
#define WAIT_VM3()   asm volatile("s_waitcnt vmcnt(3)" ::: "memory")
#define WAIT_VM0()   asm volatile("s_waitcnt vmcnt(0)" ::: "memory")

__device__ __forceinline__ unsigned short h16(float f) {
    _Float16 h = (_Float16)f;   // v_cvt_f16_f32, RTN
    return *(unsigned short*)&h;
}

// monotone map: float bits -> u32 preserving order (finite values)
__device__ __forceinline__ unsigned fkey32(float f) {
    unsigned u = __float_as_uint(f);
    return (u & 0x80000000u) ? ~u : (u | 0x80000000u);
}

// ---------- fused conversion + output-zero kernel (round-20-verified) ----------

__global__ __launch_bounds__(256) void ve_conv(const float* __restrict__ x,
        const float* __restrict__ W, unsigned short* __restrict__ xf,
        unsigned short* __restrict__ wt, unsigned int* __restrict__ cnts,
        float* __restrict__ out) {
    const int tid = threadIdx.x;
    if (blockIdx.x < 8192) {
        int i = blockIdx.x * 256 + tid;
        if (blockIdx.x == 0 && tid < M_N) cnts[tid] = 0u;
        float4 v = reinterpret_cast<const float4*>(x)[i];
        ushort4 h;
        h.x = h16(v.x); h.y = h16(v.y); h.z = h16(v.z); h.w = h16(v.w);
        reinterpret_cast<ushort4*>(xf)[i] = h;
    } else if (blockIdx.x < 9216) {
        __shared__ float t[64][65];
        const int b = blockIdx.x - 8192;
        const int c0 = (b & 15) * 64, k0 = ((b >> 4) & 7) * 64, m = b >> 7;
#pragma unroll
        for (int p = 0; p < 16; ++p) {
            int idx = p * 256 + tid;
            int kk = idx >> 6, cc = idx & 63;
            int c = c0 + cc;
            t[kk][cc] = (c < C_N) ? W[((size_t)m * D_K + k0 + kk) * C_N + c] : 0.f;
        }
        __syncthreads();
#pragma unroll
        for (int p = 0; p < 4; ++p) {
            int idx = p * 256 + tid;
            int cc = idx >> 4, kq = idx & 15;
            ushort4 h;
            h.x = h16(t[kq * 4 + 0][cc]); h.y = h16(t[kq * 4 + 1][cc]);
            h.z = h16(t[kq * 4 + 2][cc]); h.w = h16(t[kq * 4 + 3][cc]);
            size_t o = ((size_t)m * CP + c0 + cc) * D_K + k0 + kq * 4;
            *reinterpret_cast<ushort4*>(wt + o) = h;
        }
    } else {
        const int b = blockIdx.x - 9216;           // 0..1023
        float4* po = reinterpret_cast<float4*>(out) + (size_t)b * 4000;
        const float4 z = make_float4(0.f, 0.f, 0.f, 0.f);
        for (int i = tid; i < 4000; i += 256) po[i] = z;
    }
}

// -- fp16 MFMA GEMM: block 128r x 256c, 8 waves (wave 64x64), BK=32, 3-buf --
// LDS byte layout bit-identical to round 17/19 (verified): subtile 8KB =
// [128 x 32k] paired-row XOR-swizzle, inverse on global source; one
// 512-thread gload writes exactly the bytes two 256-thread gloads wrote.
// stage = 3 gloads; counted vmcnt(3) (2-deep). 72KB LDS -> 2 blocks/CU
// = 16 waves/CU = 4 waves/SIMD (double the issue candidates of r17).

__global__ __launch_bounds__(512, 4) void ve_gemm16d(
        const unsigned short* __restrict__ Xf, const unsigned short* __restrict__ WT,
        const float* __restrict__ bias, float4* __restrict__ part) {
    __shared__ unsigned short At[12288];   // 24 KB: 3 bufs x [128r x 32k]
    __shared__ unsigned short Bt[24576];   // 48 KB: 3 bufs x 2 subtiles

    const int tid = threadIdx.x;
    const int l = tid & 63, w = tid >> 6;      // 8 waves
    const int wr = w >> 2, wc = w & 3;         // wave = rows wr*64, cols wc*64
    const int l15 = l & 15, kg = l >> 4;
    const int bid = blockIdx.x;
    const int mb = bid & 7, ct = (bid >> 3) & 3, rt = bid >> 5;
    const int r0 = rt * 128, c0 = ct * 256;

    // staging lane constants (verified inverse swizzle); w in [0,8) covers
    // all 128 rows/cols of a subtile in 16-row strips.
    const int lhi = l >> 3, llo = l & 7;
    const int s3g = llo ^ lhi;
    const int w16s = w * 16 + ((lhi << 1) | (s3g >> 2));
    const int kgs = (s3g & 3) * 8;             // shorts

    const unsigned short* xA   = Xf + (size_t)(r0 + w16s) * D_K + kgs;
    const unsigned short* xBs0 = WT + (size_t)(mb * CP + c0 +       w16s) * D_K + kgs;
    const unsigned short* xBs1 = WT + (size_t)(mb * CP + c0 + 128 + w16s) * D_K + kgs;

    auto stage = [&](int t, int buf) {         // 3 gloads: A tile + 2 B subtiles
        gload16(xA   + t * 32, At + buf * 4096 + tid * 8);
        gload16(xBs0 + t * 32, Bt + buf * 8192 + tid * 8);
        gload16(xBs1 + t * 32, Bt + buf * 8192 + 4096 + tid * 8);
    };

    // fragment read byte-offsets within buffer 0 (verified formula)
    auto ldsoff = [&](int row, int kc) {
        return (row >> 1) * 64 + (((((row & 1) << 2) | kc) ^ ((row >> 1) & 7)) * 8);
    };
    const char* aP[4]; const char* bP[4];
#pragma unroll
    for (int i = 0; i < 4; ++i)
        aP[i] = (const char*)At + 2 * ldsoff(wr * 64 + i * 16 + l15, kg);
#pragma unroll
    for (int j = 0; j < 4; ++j)
        bP[j] = (const char*)Bt + (wc >> 1) * 8192
              + 2 * ldsoff((wc & 1) * 64 + j * 16 + l15, kg);

    f32x4 acc[4][4];
#pragma unroll
    for (int i = 0; i < 4; ++i)
#pragma unroll
        for (int j = 0; j < 4; ++j) acc[i][j] = (f32x4){0.f, 0.f, 0.f, 0.f};

    stage(0, 0);
    stage(1, 1);
    WAIT_VM3();
    BAR();

#pragma unroll 1
    for (int t = 0; t < 16; ++t) {
        if (t < 14) stage(t + 2, (t + 2) % 3);
        const int curA = (t % 3) * 8192;       // bytes
        const int curB = (t % 3) * 16384;      // bytes

        f16x8 af[4], bf[4];
#pragma unroll
        for (int i = 0; i < 4; ++i) af[i] = *reinterpret_cast<const f16x8*>(aP[i] + curA);
#pragma unroll
        for (int j = 0; j < 4; ++j) bf[j] = *reinterpret_cast<const f16x8*>(bP[j] + curB);
#pragma unroll
        for (int i = 0; i < 4; ++i)
#pragma unroll
            for (int j = 0; j < 4; ++j)
                acc[i][j] = __builtin_amdgcn_mfma_f32_16x16x32_f16(af[i], bf[j], acc[i][j], 0, 0, 0);

        // counted wait: stage(t+1) landed; stage(t+2) stays in flight.
        if (t < 14)       { WAIT_VM3(); }
        else if (t == 14) { WAIT_VM0(); }
        WAIT_LGKM0();
        BAR();
    }

    // ---------------- epilogue: bias + cheap running top-2 ----------------
    float4 (*wtop)[4] = reinterpret_cast<float4(*)[4]>(At);   // 8KB, overlays dead At

    float bv[4]; int cg[4];
#pragma unroll
    for (int j = 0; j < 4; ++j) {
        int c = c0 + wc * 64 + j * 16 + l15;
        cg[j] = c;
        bv[j] = (c < C_N) ? bias[mb * C_N + c] : -1e30f;
    }
#pragma unroll
    for (int i = 0; i < 4; ++i) {
#pragma unroll
        for (int reg = 0; reg < 4; ++reg) {
            float v1 = acc[i][0][reg] + bv[0]; int i1 = cg[0];
            float v2 = -1e30f;
#pragma unroll
            for (int j = 1; j < 4; ++j) {
                float v = acc[i][j][reg] + bv[j];
                float mn = fminf(v, v1);
                v2 = fmaxf(v2, mn);
                i1 = (v > v1) ? cg[j] : i1;
                v1 = fmaxf(v1, v);
            }
#pragma unroll
            for (int mask = 1; mask < 16; mask <<= 1) {
                float ov1 = __shfl_xor(v1, mask);
                int   oi1 = __shfl_xor(i1, mask);
                float ov2 = __shfl_xor(v2, mask);
                float mn = fminf(v1, ov1);
                v2 = fmaxf(fmaxf(v2, ov2), mn);
                i1 = (ov1 > v1) ? oi1 : i1;
                v1 = fmaxf(v1, ov1);
            }
            if (l15 == 0) {
                int row = wr * 64 + i * 16 + (l >> 4) * 4 + reg;
                wtop[row][wc] = make_float4(v1, __int_as_float(i1), v2, 0.f);
            }
        }
    }
    __syncthreads();
    if (tid < 128) {
        float4 o = wtop[tid][0];
        float v1 = o.x; int i1 = __float_as_int(o.y); float v2 = o.z;
#pragma unroll
        for (int s = 1; s < 4; ++s) {
            float4 q = wtop[tid][s];
            if (q.x > v1) {
                v2 = fmaxf(v1, fmaxf(q.z, v2));
                v1 = q.x; i1 = __float_as_int(q.y);
            } else {
                v2 = fmaxf(v2, q.x);
            }
        }
        part[((size_t)mb * B_N + r0 + tid) * 4 + ct] =
            make_float4(v1, __int_as_float(i1), v2, 0.f);
    }
}

// -------- merge 4 C-tiles, approx argmax, flag small-gap rows (r20-verified) --------

__global__ __launch_bounds__(128) void ve_flag4(const float4* __restrict__ part,
        unsigned int* __restrict__ wout, unsigned int* __restrict__ rlist,
        unsigned int* __restrict__ cnts, unsigned long long* __restrict__ fixkey) {
    int r = blockIdx.x * 128 + threadIdx.x;
#pragma unroll
    for (int m = 0; m < M_N; ++m) {
        float4 o = part[((size_t)m * B_N + r) * 4 + 0];
        float v1 = o.x; int i1 = __float_as_int(o.y); float v2 = o.z;
#pragma unroll
        for (int t = 1; t < 4; ++t) {
            float4 q = part[((size_t)m * B_N + r) * 4 + t];
            if (q.x > v1) {
                v2 = fmaxf(v1, fmaxf(q.z, v2));
                v1 = q.x; i1 = __float_as_int(q.y);
            } else {
                v2 = fmaxf(v2, q.x);
            }
        }
        if (v1 - v2 <= GAP_EPS) {
            wout[m * B_N + r] = (unsigned)i1 | 0x80000000u;
            fixkey[m * B_N + r] = 0ull;
            unsigned pos = atomicAdd(&cnts[m], 1u);
            rlist[m * B_N + pos] = (unsigned)r;
        } else {
            wout[m * B_N + r] = (unsigned)i1;
        }
    }
}

// -------- grouped exact pass (r20-verified): atomicMax packed key --------

__global__ __launch_bounds__(256) void ve_exact_g(
        const float* __restrict__ x, const float* __restrict__ W,
        const float* __restrict__ bias, const unsigned int* __restrict__ rlist,
        const unsigned int* __restrict__ cnts, unsigned long long* __restrict__ fixkey) {
    __shared__ float xs[32][65];
    __shared__ float wsm[32][128];
    __shared__ int rg[64];
    const int ct = blockIdx.x, m = blockIdx.z;
    const int tid = threadIdx.x;
    const int tx = tid & 15, ty = tid >> 4;
    const int c0 = ct * 128;
    const unsigned nm = cnts[m];

    for (unsigned rb = blockIdx.y; rb * 64 < nm; rb += gridDim.y) {
        __syncthreads();
        if (tid < 64) {
            unsigned idx = rb * 64 + tid;
            rg[tid] = (idx < nm) ? (int)rlist[m * B_N + idx] : 0;
        }
        __syncthreads();

        float acc[4][8];
#pragma unroll
        for (int i = 0; i < 4; i++)
#pragma unroll
            for (int j = 0; j < 8; j++) acc[i][j] = 0.f;

        for (int kt = 0; kt < D_K; kt += 32) {
#pragma unroll
            for (int i = 0; i < 2; i++) {
                int li = tid + i * 256;
                int row = li >> 3, kq = li & 7;
                float4 v = *reinterpret_cast<const float4*>(
                        x + (size_t)rg[row] * D_K + kt + kq * 4);
                int kk = kq * 4;
                xs[kk + 0][row] = v.x; xs[kk + 1][row] = v.y;
                xs[kk + 2][row] = v.z; xs[kk + 3][row] = v.w;
            }
#pragma unroll
            for (int i = 0; i < 4; i++) {
                int li = tid + i * 256;
                int kk = li >> 5, cq = li & 31;
                int c = c0 + cq * 4;
                const float* p = W + ((size_t)(m * D_K + kt + kk)) * C_N + c;
                float4 v;
                if (c + 3 < C_N) v = *reinterpret_cast<const float4*>(p);
                else {
                    v.x = (c + 0 < C_N) ? p[0] : 0.f; v.y = (c + 1 < C_N) ? p[1] : 0.f;
                    v.z = (c + 2 < C_N) ? p[2] : 0.f; v.w = (c + 3 < C_N) ? p[3] : 0.f;
                }
                wsm[kk][cq * 4 + 0] = v.x; wsm[kk][cq * 4 + 1] = v.y;
                wsm[kk][cq * 4 + 2] = v.z; wsm[kk][cq * 4 + 3] = v.w;
            }
            __syncthreads();
            for (int kk = 0; kk < 32; kk++) {
                float a[4], bb[8];
#pragma unroll
                for (int i = 0; i < 4; i++) a[i] = xs[kk][ty + i * 16];
#pragma unroll
                for (int j = 0; j < 8; j++) bb[j] = wsm[kk][tx + j * 16];
#pragma unroll
                for (int i = 0; i < 4; i++)
#pragma unroll
                    for (int j = 0; j < 8; j++) acc[i][j] += a[i] * bb[j];
            }
            __syncthreads();
        }

        const float NEG_INF = -__builtin_huge_valf();
        float bv[8]; int cv[8];
#pragma unroll
        for (int j = 0; j < 8; j++) {
            int c = c0 + tx + j * 16;
            cv[j] = c;
            bv[j] = (c < C_N) ? bias[m * C_N + c] : 0.f;
        }
#pragma unroll
        for (int i = 0; i < 4; i++) {
            float best = NEG_INF; int bidx = 0x7fffffff;
#pragma unroll
            for (int j = 0; j < 8; j++) {
                int c = cv[j];
                float v = (c < C_N) ? (acc[i][j] + bv[j]) : NEG_INF;
                if (v > best || (v == best && c < bidx)) { best = v; bidx = c; }
            }
#pragma unroll
            for (int mask = 1; mask < 16; mask <<= 1) {
                float ov = __shfl_xor(best, mask);
                int oi = __shfl_xor(bidx, mask);
                if (ov > best || (ov == best && oi < bidx)) { best = ov; bidx = oi; }
            }
            unsigned slot = rb * 64 + ty + i * 16;
            if (tx == 0 && slot < nm) {
                unsigned long long key =
                    ((unsigned long long)fkey32(best) << 32) | (unsigned)(~(unsigned)bidx);
                atomicMax(fixkey + (size_t)m * B_N + rg[ty + i * 16], key);
            }
        }
    }
}

// -------- scatter vote (r20-verified) --------
__global__ __launch_bounds__(128) void ve_votef(const unsigned int* __restrict__ wout,
        const unsigned long long* __restrict__ fixkey,
        const float* __restrict__ coefs, float* __restrict__ out) {
    int r = blockIdx.x * 128 + threadIdx.x;
#pragma unroll
    for (int m = 0; m < M_N; ++m) {
        unsigned wv = wout[m * B_N + r];
        int idx;
        if (wv & 0x80000000u) {
            unsigned long long k = fixkey[(size_t)m * B_N + r];
            idx = (int)(~(unsigned)k);
        } else {
            idx = (int)wv;
        }
        out[(size_t)r * C_N + idx] += coefs[m] * 0.125f;
    }
}

// ================= fallback: proven round-1 fp32 path =================

#define TM 128
#define TN 128
#define TK 32
#define CT 8

__global__ __launch_bounds__(256) void ve_zero_out(float* __restrict__ out, int n4) {
    int i = blockIdx.x * blockDim.x + threadIdx.x;
    const float4 z = make_float4(0.f, 0.f, 0.f, 0.f);
    for (; i < n4; i += gridDim.x * blockDim.x)
        reinterpret_cast<float4*>(out)[i] = z;
}

__global__ __launch_bounds__(256) void ve_gemm_argmax_fb(
        const float* __restrict__ x, const float* __restrict__ W,
        const float* __restrict__ bias, float2* __restrict__ part) {
    __shared__ float xs[TK][TM + 1];
    __shared__ float ws[TK][TN];
    const int ct = blockIdx.x, rt = blockIdx.y, m = blockIdx.z;
    const int tid = threadIdx.x;
    const int tx = tid & 15, ty = tid >> 4;
    const int r0 = rt * TM, c0 = ct * TN;
    float acc[8][8];
#pragma unroll
    for (int i = 0; i < 8; i++)
#pragma unroll
        for (int j = 0; j < 8; j++) acc[i][j] = 0.f;
    const float* xbase = x + (size_t)r0 * D_K;
    for (int kt = 0; kt < D_K; kt += TK) {
#pragma unroll
        for (int i = 0; i < 4; i++) {
            int li = tid + i * 256;
            int row = li >> 3, kq = li & 7;
            float4 v = *reinterpret_cast<const float4*>(xbase + (size_t)row * D_K + kt + kq * 4);
            int kk = kq * 4;
            xs[kk + 0][row] = v.x; xs[kk + 1][row] = v.y;
            xs[kk + 2][row] = v.z; xs[kk + 3][row] = v.w;
        }
#pragma unroll
        for (int i = 0; i < 4; i++) {
            int li = tid + i * 256;
            int kk = li >> 5, cq = li & 31;
            int c = c0 + cq * 4;
            const float* p = W + ((size_t)(m * D_K + kt + kk)) * C_N + c;
            float4 v;
            if (c + 3 < C_N) v = *reinterpret_cast<const float4*>(p);
            else {
                v.x = (c + 0 < C_N) ? p[0] : 0.f; v.y = (c + 1 < C_N) ? p[1] : 0.f;
                v.z = (c + 2 < C_N) ? p[2] : 0.f; v.w = (c + 3 < C_N) ? p[3] : 0.f;
            }
            ws[kk][cq * 4 + 0] = v.x; ws[kk][cq * 4 + 1] = v.y;
            ws[kk][cq * 4 + 2] = v.z; ws[kk][cq * 4 + 3] = v.w;
        }
        __syncthreads();
        for (int kk = 0; kk < TK; kk++) {
            float a[8], bb[8];
#pragma unroll
            for (int i = 0; i < 8; i++) a[i] = xs[kk][ty + i * 16];
#pragma unroll
            for (int j = 0; j < 8; j++) bb[j] = ws[kk][tx + j * 16];
#pragma unroll
            for (int i = 0; i < 8; i++)
#pragma unroll
                for (int j = 0; j < 8; j++) acc[i][j] += a[i] * bb[j];
        }
        __syncthreads();
    }
    const float NEG_INF = -__builtin_huge_valf();
    float bv[8]; int cv[8];
#pragma unroll
    for (int j = 0; j < 8; j++) {
        int c = c0 + tx + j * 16;
        cv[j] = c;
        bv[j] = (c < C_N) ? bias[m * C_N + c] : 0.f;
    }
#pragma unroll
    for (int i = 0; i < 8; i++) {
        int r = r0 + ty + i * 16;
        float best = NEG_INF; int bidx = 0x7fffffff;
#pragma unroll
        for (int j = 0; j < 8; j++) {
            int c = cv[j];
            float v = (c < C_N) ? (acc[i][j] + bv[j]) : NEG_INF;
            if (v > best || (v == best && c < bidx)) { best = v; bidx = c; }
        }
#pragma unroll
        for (int mask = 1; mask < 16; mask <<= 1) {
            float ov = __shfl_xor(best, mask);
            int oi = __shfl_xor(bidx, mask);
            if (ov > best || (ov == best && oi < bidx)) { best = ov; bidx = oi; }
        }
        if (tx == 0) part[((size_t)m * B_N + r) * CT + ct] = make_float2(best, __int_as_float(bidx));
    }
}

__global__ __launch_bounds__(256) void ve_vote_fb(const float2* __restrict__ part,
        const float* __restrict__ coefs, float* __restrict__ out) {
    int r = blockIdx.x * blockDim.x + threadIdx.x;
    if (r >= B_N) return;
    const float NEG_INF = -__builtin_huge_valf();
#pragma unroll
    for (int m = 0; m < M_N; m++) {
        float best = NEG_INF; int bidx = 0x7fffffff;
#pragma unroll
        for (int ctt = 0; ctt < CT; ctt++) {
            float2 p = part[((size_t)m * B_N + r) * CT + ctt];
            int oi = __float_as_int(p.y);
            if (p.x > best || (p.x == best && oi < bidx)) { best = p.x; bidx = oi; }
        }
        out[(size_t)r * C_N + bidx] += coefs[m] * 0.125f;
    }
}

// ================= launcher =================

extern "C" void kernel_launch(void* const* d_in, const int* in_sizes, int n_in,
                              void* d_out, int out_size, void* d_ws, size_t ws_size,
                              hipStream_t stream) {
    const float* x     = (const float*)d_in[0];
    const float* W     = (const float*)d_in[1];
    const float* bias  = (const float*)d_in[2];
    const float* coefs = (const float*)d_in[3];
    float* out = (float*)d_out;

    const size_t NEED = (57ull << 20) + 4096;
    if (ws_size >= NEED) {
        char* ws = (char*)d_ws;
        unsigned short*     Xf     = (unsigned short*)(ws);                  // 16 MiB
        unsigned short*     WT16   = (unsigned short*)(ws + (16ull << 20));  //  8 MiB
        float4*             part   = (float4*)(ws + (24ull << 20));          //  8 MiB
        unsigned long long* fixkey = (unsigned long long*)(ws + (40ull << 20)); // 1 MiB
        unsigned int*       wout   = (unsigned int*)(ws + (48ull << 20));    // 512 KiB
        unsigned int*       rlist  = (unsigned int*)(ws + (48ull << 20) + (512ull << 10)); // 512 KiB
        unsigned int*       cnts   = (unsigned int*)(ws + (49ull << 20));    // 32 B

        ve_conv<<<10240, 256, 0, stream>>>(x, W, Xf, WT16, cnts, out);
        ve_gemm16d<<<4096, 512, 0, stream>>>(Xf, WT16, bias, part);
        ve_flag4<<<128, 128, 0, stream>>>(part, wout, rlist, cnts, fixkey);
        ve_exact_g<<<dim3(8, 8, 8), 256, 0, stream>>>(x, W, bias, rlist, cnts, fixkey);
        ve_votef<<<128, 128, 0, stream>>>(wout, fixkey, coefs, out);
    } else {
        float2* partf = (float2*)d_ws;
        ve_zero_out<<<2048, 256, 0, stream>>>(out, B_N * C_N / 4);
        dim3 grid(CT, B_N / TM, M_N);
        ve_gemm_argmax_fb<<<grid, 256, 0, stream>>>(x, W, bias, partf);
        ve_vote_fb<<<(B_N + 255) / 256, 256, 0, stream>>>(partf, coefs, out);
    }
}

// Round 22
// 310.532 us; speedup vs baseline: 1.0421x; 1.0421x over previous
//
#include <hip/hip_runtime.h>

#define B_N 16384
#define D_K 512
#define C_N 1000
#define CP 1024
#define M_N 8
#define GAP_EPS 1e-3f

typedef __attribute__((ext_vector_type(8))) _Float16 f16x8;
typedef __attribute__((ext_vector_type(4))) float f32x4;

typedef const __attribute__((address_space(1))) unsigned int* gptr_t;
typedef __attribute__((address_space(3))) unsigned int* lptr_t;

__device__ __forceinline__ void gload16(const void* g, void* l) {
    __builtin_amdgcn_global_load_lds((gptr_t)g, (lptr_t)l, 16, 0, 0);
}

#define BAR()        asm volatile("s_barrier" ::: "memory")
#define WAIT_LGKM0() asm volatile("s_waitcnt lgkmcnt(0)" ::: "memory")
#define WAIT_VM6()   asm volatile("s_waitcnt vmcnt(6)" ::: "memory")
#define WAIT_VM0()   asm volatile("s_waitcnt vmcnt(0)" ::: "memory")

__device__ __forceinline__ unsigned short h16(float f) {
    _Float16 h = (_Float16)f;   // v_cvt_f16_f32, RTN
    return *(unsigned short*)&h;
}

// monotone map: float bits -> u32 preserving order (finite values)
__device__ __forceinline__ unsigned fkey32(float f) {
    unsigned u = __float_as_uint(f);
    return (u & 0x80000000u) ? ~u : (u | 0x80000000u);
}

// ---------- fused conversion + output-zero kernel ----------
// [0,8192): x fp32->fp16 ; [8192,9216): W -> WT16 ; [9216,10240): zero out

__global__ __launch_bounds__(256) void ve_conv(const float* __restrict__ x,
        const float* __restrict__ W, unsigned short* __restrict__ xf,
        unsigned short* __restrict__ wt, unsigned int* __restrict__ cnts,
        float* __restrict__ out) {
    const int tid = threadIdx.x;
    if (blockIdx.x < 8192) {
        int i = blockIdx.x * 256 + tid;
        if (blockIdx.x == 0 && tid < M_N) cnts[tid] = 0u;
        float4 v = reinterpret_cast<const float4*>(x)[i];
        ushort4 h;
        h.x = h16(v.x); h.y = h16(v.y); h.z = h16(v.z); h.w = h16(v.w);
        reinterpret_cast<ushort4*>(xf)[i] = h;
    } else if (blockIdx.x < 9216) {
        __shared__ float t[64][65];
        const int b = blockIdx.x - 8192;
        const int c0 = (b & 15) * 64, k0 = ((b >> 4) & 7) * 64, m = b >> 7;
#pragma unroll
        for (int p = 0; p < 16; ++p) {
            int idx = p * 256 + tid;
            int kk = idx >> 6, cc = idx & 63;
            int c = c0 + cc;
            t[kk][cc] = (c < C_N) ? W[((size_t)m * D_K + k0 + kk) * C_N + c] : 0.f;
        }
        __syncthreads();
#pragma unroll
        for (int p = 0; p < 4; ++p) {
            int idx = p * 256 + tid;
            int cc = idx >> 4, kq = idx & 15;
            ushort4 h;
            h.x = h16(t[kq * 4 + 0][cc]); h.y = h16(t[kq * 4 + 1][cc]);
            h.z = h16(t[kq * 4 + 2][cc]); h.w = h16(t[kq * 4 + 3][cc]);
            size_t o = ((size_t)m * CP + c0 + cc) * D_K + k0 + kq * 4;
            *reinterpret_cast<ushort4*>(wt + o) = h;
        }
    } else {
        const int b = blockIdx.x - 9216;           // 0..1023
        float4* po = reinterpret_cast<float4*>(out) + (size_t)b * 4000;
        const float4 z = make_float4(0.f, 0.f, 0.f, 0.f);
        for (int i = tid; i < 4000; i += 256) po[i] = z;
    }
}

// -- fp16 MFMA GEMM: block 128r x 256c, 4 waves (wave 64x128), BK=32, 3-buf --
// Round-17/19/20-verified (222us, absmax 0.0).

__global__ __launch_bounds__(256, 2) void ve_gemm16d(
        const unsigned short* __restrict__ Xf, const unsigned short* __restrict__ WT,
        const float* __restrict__ bias, float4* __restrict__ part) {
    __shared__ unsigned short At[12288];   // 24 KB: 3 bufs x [128r x 32k]
    __shared__ unsigned short Bt[24576];   // 48 KB: 3 bufs x 2 subtiles

    const int tid = threadIdx.x;
    const int l = tid & 63, w = tid >> 6;
    const int wr = w >> 1, wc = w & 1;        // wave = rows wr*64, cols wc*128
    const int l15 = l & 15, kg = l >> 4;
    const int bid = blockIdx.x;
    const int mb = bid & 7, ct = (bid >> 3) & 3, rt = bid >> 5;
    const int r0 = rt * 128, c0 = ct * 256;

    // staging lane constants (round-9-verified inverse swizzle)
    const int lhi = l >> 3, llo = l & 7;
    const int s3g = llo ^ lhi;
    const int srow16 = (lhi << 1) | (s3g >> 2);
    const int kgs = (s3g & 3) * 8;            // shorts

    const unsigned short* xA0 = Xf + (size_t)(r0 +      w * 16 + srow16) * D_K + kgs;
    const unsigned short* xA1 = Xf + (size_t)(r0 + 64 + w * 16 + srow16) * D_K + kgs;
    const unsigned short* xB0 = WT + (size_t)(mb * CP + c0 +       w * 16 + srow16) * D_K + kgs;
    const unsigned short* xB1 = WT + (size_t)(mb * CP + c0 +  64 + w * 16 + srow16) * D_K + kgs;
    const unsigned short* xB2 = WT + (size_t)(mb * CP + c0 + 128 + w * 16 + srow16) * D_K + kgs;
    const unsigned short* xB3 = WT + (size_t)(mb * CP + c0 + 192 + w * 16 + srow16) * D_K + kgs;

    auto stage = [&](int t, int buf) {        // 6 gloads: A tile + 2 B subtiles
        unsigned short* A = At + buf * 4096;
        unsigned short* B = Bt + buf * 8192;
        gload16(xA0 + t * 32, A + tid * 8);
        gload16(xA1 + t * 32, A + 2048 + tid * 8);
        gload16(xB0 + t * 32, B + tid * 8);
        gload16(xB1 + t * 32, B + 2048 + tid * 8);
        gload16(xB2 + t * 32, B + 4096 + tid * 8);
        gload16(xB3 + t * 32, B + 6144 + tid * 8);
    };

    auto ldsoff = [&](int row, int kc) {
        return (row >> 1) * 64 + (((((row & 1) << 2) | kc) ^ ((row >> 1) & 7)) * 8);
    };
    const char* aP[4]; const char* bP[8];
#pragma unroll
    for (int i = 0; i < 4; ++i)
        aP[i] = (const char*)At + 2 * ldsoff(wr * 64 + i * 16 + l15, kg);
#pragma unroll
    for (int j = 0; j < 8; ++j)
        bP[j] = (const char*)Bt + wc * 8192 + 2 * ldsoff(j * 16 + l15, kg);

    f32x4 acc[4][8];
#pragma unroll
    for (int i = 0; i < 4; ++i)
#pragma unroll
        for (int j = 0; j < 8; ++j) acc[i][j] = (f32x4){0.f, 0.f, 0.f, 0.f};

    stage(0, 0);
    stage(1, 1);
    WAIT_VM6();
    BAR();

#pragma unroll 1
    for (int t = 0; t < 16; ++t) {
        if (t < 14) stage(t + 2, (t + 2) % 3);
        const int curA = (t % 3) * 8192;
        const int curB = (t % 3) * 16384;

        f16x8 af[4], bf[8];
#pragma unroll
        for (int i = 0; i < 4; ++i) af[i] = *reinterpret_cast<const f16x8*>(aP[i] + curA);
#pragma unroll
        for (int j = 0; j < 8; ++j) bf[j] = *reinterpret_cast<const f16x8*>(bP[j] + curB);
        __builtin_amdgcn_s_setprio(1);
#pragma unroll
        for (int i = 0; i < 4; ++i)
#pragma unroll
            for (int j = 0; j < 8; ++j)
                acc[i][j] = __builtin_amdgcn_mfma_f32_16x16x32_f16(af[i], bf[j], acc[i][j], 0, 0, 0);
        __builtin_amdgcn_s_setprio(0);

        if (t < 14)       { WAIT_VM6(); }
        else if (t == 14) { WAIT_VM0(); }
        WAIT_LGKM0();
        BAR();
    }

    // ---------------- epilogue: bias + cheap running top-2 ----------------
    float4 (*wtop)[2] = reinterpret_cast<float4(*)[2]>(At);

    float bv[8]; int cg[8];
#pragma unroll
    for (int j = 0; j < 8; ++j) {
        int c = c0 + wc * 128 + j * 16 + l15;
        cg[j] = c;
        bv[j] = (c < C_N) ? bias[mb * C_N + c] : -1e30f;
    }
#pragma unroll
    for (int i = 0; i < 4; ++i) {
#pragma unroll
        for (int reg = 0; reg < 4; ++reg) {
            float v1 = acc[i][0][reg] + bv[0]; int i1 = cg[0];
            float v2 = -1e30f;
#pragma unroll
            for (int j = 1; j < 8; ++j) {
                float v = acc[i][j][reg] + bv[j];
                float mn = fminf(v, v1);
                v2 = fmaxf(v2, mn);
                i1 = (v > v1) ? cg[j] : i1;
                v1 = fmaxf(v1, v);
            }
#pragma unroll
            for (int mask = 1; mask < 16; mask <<= 1) {
                float ov1 = __shfl_xor(v1, mask);
                int   oi1 = __shfl_xor(i1, mask);
                float ov2 = __shfl_xor(v2, mask);
                float mn = fminf(v1, ov1);
                v2 = fmaxf(fmaxf(v2, ov2), mn);
                i1 = (ov1 > v1) ? oi1 : i1;
                v1 = fmaxf(v1, ov1);
            }
            if (l15 == 0) {
                int row = wr * 64 + i * 16 + (l >> 4) * 4 + reg;
                wtop[row][wc] = make_float4(v1, __int_as_float(i1), v2, 0.f);
            }
        }
    }
    __syncthreads();
    if (tid < 128) {
        float4 a = wtop[tid][0], b = wtop[tid][1];
        float v1, v2; int i1;
        if (b.x > a.x) {
            v1 = b.x; i1 = __float_as_int(b.y);
            v2 = fmaxf(a.x, b.z);
        } else {
            v1 = a.x; i1 = __float_as_int(a.y);
            v2 = fmaxf(b.x, a.z);
        }
        part[((size_t)mb * B_N + r0 + tid) * 4 + ct] =
            make_float4(v1, __int_as_float(i1), v2, 0.f);
    }
}

// -------- merge 4 C-tiles, approx argmax, flag small-gap rows --------
// Flagged rows: wout bit-31 set, fixkey zero-initialized.

__global__ __launch_bounds__(128) void ve_flag4(const float4* __restrict__ part,
        unsigned int* __restrict__ wout, unsigned int* __restrict__ rlist,
        unsigned int* __restrict__ cnts, unsigned long long* __restrict__ fixkey) {
    int r = blockIdx.x * 128 + threadIdx.x;
#pragma unroll
    for (int m = 0; m < M_N; ++m) {
        float4 o = part[((size_t)m * B_N + r) * 4 + 0];
        float v1 = o.x; int i1 = __float_as_int(o.y); float v2 = o.z;
#pragma unroll
        for (int t = 1; t < 4; ++t) {
            float4 q = part[((size_t)m * B_N + r) * 4 + t];
            if (q.x > v1) {
                v2 = fmaxf(v1, fmaxf(q.z, v2));
                v1 = q.x; i1 = __float_as_int(q.y);
            } else {
                v2 = fmaxf(v2, q.x);
            }
        }
        if (v1 - v2 <= GAP_EPS) {
            wout[m * B_N + r] = (unsigned)i1 | 0x80000000u;
            fixkey[m * B_N + r] = 0ull;
            unsigned pos = atomicAdd(&cnts[m], 1u);
            rlist[m * B_N + pos] = (unsigned)r;
        } else {
            wout[m * B_N + r] = (unsigned)i1;
        }
    }
}

// -------- grouped exact pass: 64 rows/block; atomicMax packed key --------
// Serial-k fp32 FMA accumulation per row unchanged (numpy-matching).
// key = (fkey32(value)<<32) | ~idx  -> max key == max value, lowest idx on tie.

__global__ __launch_bounds__(256) void ve_exact_g(
        const float* __restrict__ x, const float* __restrict__ W,
        const float* __restrict__ bias, const unsigned int* __restrict__ rlist,
        const unsigned int* __restrict__ cnts, unsigned long long* __restrict__ fixkey) {
    __shared__ float xs[32][65];
    __shared__ float wsm[32][128];
    __shared__ int rg[64];
    const int ct = blockIdx.x, m = blockIdx.z;
    const int tid = threadIdx.x;
    const int tx = tid & 15, ty = tid >> 4;
    const int c0 = ct * 128;
    const unsigned nm = cnts[m];

    for (unsigned rb = blockIdx.y; rb * 64 < nm; rb += gridDim.y) {
        __syncthreads();
        if (tid < 64) {
            unsigned idx = rb * 64 + tid;
            rg[tid] = (idx < nm) ? (int)rlist[m * B_N + idx] : 0;
        }
        __syncthreads();

        float acc[4][8];
#pragma unroll
        for (int i = 0; i < 4; i++)
#pragma unroll
            for (int j = 0; j < 8; j++) acc[i][j] = 0.f;

        for (int kt = 0; kt < D_K; kt += 32) {
#pragma unroll
            for (int i = 0; i < 2; i++) {
                int li = tid + i * 256;
                int row = li >> 3, kq = li & 7;
                float4 v = *reinterpret_cast<const float4*>(
                        x + (size_t)rg[row] * D_K + kt + kq * 4);
                int kk = kq * 4;
                xs[kk + 0][row] = v.x; xs[kk + 1][row] = v.y;
                xs[kk + 2][row] = v.z; xs[kk + 3][row] = v.w;
            }
#pragma unroll
            for (int i = 0; i < 4; i++) {
                int li = tid + i * 256;
                int kk = li >> 5, cq = li & 31;
                int c = c0 + cq * 4;
                const float* p = W + ((size_t)(m * D_K + kt + kk)) * C_N + c;
                float4 v;
                if (c + 3 < C_N) v = *reinterpret_cast<const float4*>(p);
                else {
                    v.x = (c + 0 < C_N) ? p[0] : 0.f; v.y = (c + 1 < C_N) ? p[1] : 0.f;
                    v.z = (c + 2 < C_N) ? p[2] : 0.f; v.w = (c + 3 < C_N) ? p[3] : 0.f;
                }
                wsm[kk][cq * 4 + 0] = v.x; wsm[kk][cq * 4 + 1] = v.y;
                wsm[kk][cq * 4 + 2] = v.z; wsm[kk][cq * 4 + 3] = v.w;
            }
            __syncthreads();
            for (int kk = 0; kk < 32; kk++) {
                float a[4], bb[8];
#pragma unroll
                for (int i = 0; i < 4; i++) a[i] = xs[kk][ty + i * 16];
#pragma unroll
                for (int j = 0; j < 8; j++) bb[j] = wsm[kk][tx + j * 16];
#pragma unroll
                for (int i = 0; i < 4; i++)
#pragma unroll
                    for (int j = 0; j < 8; j++) acc[i][j] += a[i] * bb[j];
            }
            __syncthreads();
        }

        const float NEG_INF = -__builtin_huge_valf();
        float bv[8]; int cv[8];
#pragma unroll
        for (int j = 0; j < 8; j++) {
            int c = c0 + tx + j * 16;
            cv[j] = c;
            bv[j] = (c < C_N) ? bias[m * C_N + c] : 0.f;
        }
#pragma unroll
        for (int i = 0; i < 4; i++) {
            float best = NEG_INF; int bidx = 0x7fffffff;
#pragma unroll
            for (int j = 0; j < 8; j++) {
                int c = cv[j];
                float v = (c < C_N) ? (acc[i][j] + bv[j]) : NEG_INF;
                if (v > best || (v == best && c < bidx)) { best = v; bidx = c; }
            }
#pragma unroll
            for (int mask = 1; mask < 16; mask <<= 1) {
                float ov = __shfl_xor(best, mask);
                int oi = __shfl_xor(bidx, mask);
                if (ov > best || (ov == best && oi < bidx)) { best = ov; bidx = oi; }
            }
            unsigned slot = rb * 64 + ty + i * 16;
            if (tx == 0 && slot < nm) {
                unsigned long long key =
                    ((unsigned long long)fkey32(best) << 32) | (unsigned)(~(unsigned)bidx);
                atomicMax(fixkey + (size_t)m * B_N + rg[ty + i * 16], key);
            }
        }
    }
}

// -------- scatter vote: one thread per row; decode fixkey for flagged --------
__global__ __launch_bounds__(128) void ve_votef(const unsigned int* __restrict__ wout,
        const unsigned long long* __restrict__ fixkey,
        const float* __restrict__ coefs, float* __restrict__ out) {
    int r = blockIdx.x * 128 + threadIdx.x;
#pragma unroll
    for (int m = 0; m < M_N; ++m) {
        unsigned wv = wout[m * B_N + r];
        int idx;
        if (wv & 0x80000000u) {
            unsigned long long k = fixkey[(size_t)m * B_N + r];
            idx = (int)(~(unsigned)k);
        } else {
            idx = (int)wv;
        }
        out[(size_t)r * C_N + idx] += coefs[m] * 0.125f;
    }
}

// ================= fallback: proven round-1 fp32 path =================

#define TM 128
#define TN 128
#define TK 32
#define CT 8

__global__ __launch_bounds__(256) void ve_zero_out(float* __restrict__ out, int n4) {
    int i = blockIdx.x * blockDim.x + threadIdx.x;
    const float4 z = make_float4(0.f, 0.f, 0.f, 0.f);
    for (; i < n4; i += gridDim.x * blockDim.x)
        reinterpret_cast<float4*>(out)[i] = z;
}

__global__ __launch_bounds__(256) void ve_gemm_argmax_fb(
        const float* __restrict__ x, const float* __restrict__ W,
        const float* __restrict__ bias, float2* __restrict__ part) {
    __shared__ float xs[TK][TM + 1];
    __shared__ float ws[TK][TN];
    const int ct = blockIdx.x, rt = blockIdx.y, m = blockIdx.z;
    const int tid = threadIdx.x;
    const int tx = tid & 15, ty = tid >> 4;
    const int r0 = rt * TM, c0 = ct * TN;
    float acc[8][8];
#pragma unroll
    for (int i = 0; i < 8; i++)
#pragma unroll
        for (int j = 0; j < 8; j++) acc[i][j] = 0.f;
    const float* xbase = x + (size_t)r0 * D_K;
    for (int kt = 0; kt < D_K; kt += TK) {
#pragma unroll
        for (int i = 0; i < 4; i++) {
            int li = tid + i * 256;
            int row = li >> 3, kq = li & 7;
            float4 v = *reinterpret_cast<const float4*>(xbase + (size_t)row * D_K + kt + kq * 4);
            int kk = kq * 4;
            xs[kk + 0][row] = v.x; xs[kk + 1][row] = v.y;
            xs[kk + 2][row] = v.z; xs[kk + 3][row] = v.w;
        }
#pragma unroll
        for (int i = 0; i < 4; i++) {
            int li = tid + i * 256;
            int kk = li >> 5, cq = li & 31;
            int c = c0 + cq * 4;
            const float* p = W + ((size_t)(m * D_K + kt + kk)) * C_N + c;
            float4 v;
            if (c + 3 < C_N) v = *reinterpret_cast<const float4*>(p);
            else {
                v.x = (c + 0 < C_N) ? p[0] : 0.f; v.y = (c + 1 < C_N) ? p[1] : 0.f;
                v.z = (c + 2 < C_N) ? p[2] : 0.f; v.w = (c + 3 < C_N) ? p[3] : 0.f;
            }
            ws[kk][cq * 4 + 0] = v.x; ws[kk][cq * 4 + 1] = v.y;
            ws[kk][cq * 4 + 2] = v.z; ws[kk][cq * 4 + 3] = v.w;
        }
        __syncthreads();
        for (int kk = 0; kk < TK; kk++) {
            float a[8], bb[8];
#pragma unroll
            for (int i = 0; i < 8; i++) a[i] = xs[kk][ty + i * 16];
#pragma unroll
            for (int j = 0; j < 8; j++) bb[j] = ws[kk][tx + j * 16];
#pragma unroll
            for (int i = 0; i < 8; i++)
#pragma unroll
                for (int j = 0; j < 8; j++) acc[i][j] += a[i] * bb[j];
        }
        __syncthreads();
    }
    const float NEG_INF = -__builtin_huge_valf();
    float bv[8]; int cv[8];
#pragma unroll
    for (int j = 0; j < 8; j++) {
        int c = c0 + tx + j * 16;
        cv[j] = c;
        bv[j] = (c < C_N) ? bias[m * C_N + c] : 0.f;
    }
#pragma unroll
    for (int i = 0; i < 8; i++) {
        int r = r0 + ty + i * 16;
        float best = NEG_INF; int bidx = 0x7fffffff;
#pragma unroll
        for (int j = 0; j < 8; j++) {
            int c = cv[j];
            float v = (c < C_N) ? (acc[i][j] + bv[j]) : NEG_INF;
            if (v > best || (v == best && c < bidx)) { best = v; bidx = c; }
        }
#pragma unroll
        for (int mask = 1; mask < 16; mask <<= 1) {
            float ov = __shfl_xor(best, mask);
            int oi = __shfl_xor(bidx, mask);
            if (ov > best || (ov == best && oi < bidx)) { best = ov; bidx = oi; }
        }
        if (tx == 0) part[((size_t)m * B_N + r) * CT + ct] = make_float2(best, __int_as_float(bidx));
    }
}

__global__ __launch_bounds__(256) void ve_vote_fb(const float2* __restrict__ part,
        const float* __restrict__ coefs, float* __restrict__ out) {
    int r = blockIdx.x * blockDim.x + threadIdx.x;
    if (r >= B_N) return;
    const float NEG_INF = -__builtin_huge_valf();
#pragma unroll
    for (int m = 0; m < M_N; m++) {
        float best = NEG_INF; int bidx = 0x7fffffff;
#pragma unroll
        for (int ctt = 0; ctt < CT; ctt++) {
            float2 p = part[((size_t)m * B_N + r) * CT + ctt];
            int oi = __float_as_int(p.y);
            if (p.x > best || (p.x == best && oi < bidx)) { best = p.x; bidx = oi; }
        }
        out[(size_t)r * C_N + bidx] += coefs[m] * 0.125f;
    }
}

// ================= launcher =================

extern "C" void kernel_launch(void* const* d_in, const int* in_sizes, int n_in,
                              void* d_out, int out_size, void* d_ws, size_t ws_size,
                              hipStream_t stream) {
    const float* x     = (const float*)d_in[0];
    const float* W     = (const float*)d_in[1];
    const float* bias  = (const float*)d_in[2];
    const float* coefs = (const float*)d_in[3];
    float* out = (float*)d_out;

    const size_t NEED = (57ull << 20) + 4096;
    if (ws_size >= NEED) {
        char* ws = (char*)d_ws;
        unsigned short*     Xf     = (unsigned short*)(ws);                  // 16 MiB
        unsigned short*     WT16   = (unsigned short*)(ws + (16ull << 20));  //  8 MiB
        float4*             part   = (float4*)(ws + (24ull << 20));          //  8 MiB
        unsigned long long* fixkey = (unsigned long long*)(ws + (40ull << 20)); // 1 MiB
        unsigned int*       wout   = (unsigned int*)(ws + (48ull << 20));    // 512 KiB
        unsigned int*       rlist  = (unsigned int*)(ws + (48ull << 20) + (512ull << 10)); // 512 KiB
        unsigned int*       cnts   = (unsigned int*)(ws + (49ull << 20));    // 32 B

        ve_conv<<<10240, 256, 0, stream>>>(x, W, Xf, WT16, cnts, out);
        ve_gemm16d<<<4096, 256, 0, stream>>>(Xf, WT16, bias, part);
        ve_flag4<<<128, 128, 0, stream>>>(part, wout, rlist, cnts, fixkey);
        ve_exact_g<<<dim3(8, 8, 8), 256, 0, stream>>>(x, W, bias, rlist, cnts, fixkey);
        ve_votef<<<128, 128, 0, stream>>>(wout, fixkey, coefs, out);
    } else {
        float2* partf = (float2*)d_ws;
        ve_zero_out<<<2048, 256, 0, stream>>>(out, B_N * C_N / 4);
        dim3 grid(CT, B_N / TM, M_N);
        ve_gemm_argmax_fb<<<grid, 256, 0, stream>>>(x, W, bias, partf);
        ve_vote_fb<<<(B_N + 255) / 256, 256, 0, stream>>>(partf, coefs, out);
    }
}